// Round 4
// baseline (626.072 us; speedup 1.0000x reference)
//
#include <hip/hip_runtime.h>
#include <hip/hip_bf16.h>
#include <hip/hip_fp16.h>
#include <string.h>

typedef __hip_bfloat16 bf16;
typedef _Float16 f16;
typedef __attribute__((ext_vector_type(8))) short short8;
typedef __attribute__((ext_vector_type(4))) float floatx4;
typedef __attribute__((ext_vector_type(4))) unsigned int uintx4;

// async global->LDS, 16B per lane; LDS dest is wave-uniform base + lane*16
#define GLD16(gp, lp) __builtin_amdgcn_global_load_lds( \
    (__attribute__((address_space(1))) void*)(gp),      \
    (__attribute__((address_space(3))) void*)(lp), 16, 0, 0)

__device__ __forceinline__ unsigned short bf16_bits(float f) {
  bf16 h = (bf16)f;
  unsigned short s;
  memcpy(&s, &h, 2);
  return s;
}

// ---------------------------------------------------------------------------
// x (f32, [4][4096][1024]) -> bf16, staged into the low 8 MB of each d_out
// quarter. 8 elements/thread; blocks never straddle a batch (4M % 2048 == 0).
// ---------------------------------------------------------------------------
__global__ __launch_bounds__(256)
void cvtx_k(const float* __restrict__ x, char* __restrict__ outbase) {
  size_t e = ((size_t)blockIdx.x * 256 + threadIdx.x) * 8;
  int b = (int)(e >> 22);                       // 4M elements per batch
  size_t i = e & 4194303;
  const floatx4* s = (const floatx4*)(x + e);
  floatx4 a0 = s[0], a1 = s[1];
  union { uintx4 u4; unsigned short us[8]; } w;
  w.us[0] = bf16_bits(a0.x); w.us[1] = bf16_bits(a0.y);
  w.us[2] = bf16_bits(a0.z); w.us[3] = bf16_bits(a0.w);
  w.us[4] = bf16_bits(a1.x); w.us[5] = bf16_bits(a1.y);
  w.us[6] = bf16_bits(a1.z); w.us[7] = bf16_bits(a1.w);
  *(uintx4*)((bf16*)(outbase + (size_t)b * 16777216) + i) = w.u4;
}

// ---------------------------------------------------------------------------
// Transpose+convert 1024x1024 f32 weights: T[n][k] = bf16(W[k][n]), 3 via z.
// ---------------------------------------------------------------------------
__global__ __launch_bounds__(256)
void transpose_k(const float* __restrict__ W0, const float* __restrict__ W1,
                 const float* __restrict__ W2, bf16* __restrict__ T0,
                 bf16* __restrict__ T1, bf16* __restrict__ T2) {
  __shared__ bf16 t[64][66];                 // +2 pad: conflict-free col reads
  const float* S = blockIdx.z == 0 ? W0 : (blockIdx.z == 1 ? W1 : W2);
  bf16* Dst      = blockIdx.z == 0 ? T0 : (blockIdx.z == 1 ? T1 : T2);
  const int tx = threadIdx.x & 63, ty = threadIdx.x >> 6;
  const int kb = blockIdx.y * 64, nb = blockIdx.x * 64;
#pragma unroll
  for (int rr = 0; rr < 16; ++rr) {
    int r = ty * 16 + rr;
    t[r][tx] = (bf16)S[(size_t)(kb + r) * 1024 + nb + tx];
  }
  __syncthreads();
#pragma unroll
  for (int rr = 0; rr < 16; ++rr) {
    int r = ty * 16 + rr;
    Dst[(size_t)(nb + r) * 1024 + kb + tx] = t[tx][r];
  }
}

// ---------------------------------------------------------------------------
// h_prep[dblk][k][dd] = f16( h_filter[k][dblk*32+dd] * exp(-0.01k) ), k<512
// ---------------------------------------------------------------------------
__global__ __launch_bounds__(256)
void hprep_k(const float* __restrict__ hf, f16* __restrict__ hp) {
  int idx = blockIdx.x * 256 + threadIdx.x;   // < 32*512*32
  int dblk = idx >> 14;
  int rem = idx & 16383;
  int k = rem >> 5, dd = rem & 31;
  int d = dblk * 32 + dd;
  float val = hf[(size_t)k * 1024 + d] * __expf(-0.01f * (float)k);
  hp[idx] = (f16)val;
}

// ---------------------------------------------------------------------------
// GEMM body: C[m0..+128][n0..+128] = A[M][1024](bf16) @ Bt[1024][1024]^T + b
// Bt is [n][k] bf16, bias f32. 128x128 tile, BK=32, 4 waves, 4x4 16x16x32.
// out_mode: 0 -> bf16 store, 1 -> f16 store, 2 -> f32 store.
// ---------------------------------------------------------------------------
__device__ __forceinline__
void gemm_body(const bf16* __restrict__ A, const bf16* __restrict__ Bt,
               const float* __restrict__ bias, void* __restrict__ Cout,
               int out_mode, int m0, int n0) {
  constexpr int K = 1024;
  __shared__ __align__(16) bf16 As[128 * 32];   // [m][k], row 64B
  __shared__ __align__(16) bf16 Bs[128 * 32];   // [n][k], row 64B
  const int tid = threadIdx.x;
  const int lane = tid & 63;
  const int wave = tid >> 6;
  const int wm = wave >> 1, wn = wave & 1;
  const int r = lane & 15, q = lane >> 4;

  floatx4 acc[4][4] = {};

  // staging: slot s = issue*256 + tid; row = s>>2, kcol = (s&3)*8
  const int s0 = tid, s1 = 256 + tid;
  const bf16* gA0 = A + (size_t)(m0 + (s0 >> 2)) * K + (s0 & 3) * 8;
  const bf16* gA1 = A + (size_t)(m0 + (s1 >> 2)) * K + (s1 & 3) * 8;
  const bf16* gB0 = Bt + (size_t)(n0 + (s0 >> 2)) * K + (s0 & 3) * 8;
  const bf16* gB1 = Bt + (size_t)(n0 + (s1 >> 2)) * K + (s1 & 3) * 8;
  char* AsB = (char*)As + wave * 1024;   // wave-uniform LDS bases
  char* BsB = (char*)Bs + wave * 1024;

  for (int k0 = 0; k0 < K; k0 += 32) {
    GLD16(gA0 + k0, AsB);
    GLD16(gA1 + k0, AsB + 4096);
    GLD16(gB0 + k0, BsB);
    GLD16(gB1 + k0, BsB + 4096);
    __syncthreads();
    short8 af[4], bfr[4];
#pragma unroll
    for (int i = 0; i < 4; ++i)
      af[i] = *(const short8*)&As[(wm * 64 + i * 16 + r) * 32 + q * 8];
#pragma unroll
    for (int i = 0; i < 4; ++i)
      bfr[i] = *(const short8*)&Bs[(wn * 64 + i * 16 + r) * 32 + q * 8];
#pragma unroll
    for (int mi = 0; mi < 4; ++mi)
#pragma unroll
      for (int ni = 0; ni < 4; ++ni)
        acc[mi][ni] = __builtin_amdgcn_mfma_f32_16x16x32_bf16(
            af[mi], bfr[ni], acc[mi][ni], 0, 0, 0);
    __syncthreads();
  }

  // epilogue: C/D layout col(n)=lane&15, row(m)=(lane>>4)*4+reg
  const int cb = n0 + wn * 64;
  float bvv[4];
#pragma unroll
  for (int ni = 0; ni < 4; ++ni) bvv[ni] = bias[cb + ni * 16 + r];
#pragma unroll
  for (int mi = 0; mi < 4; ++mi) {
    int rowb = m0 + wm * 64 + mi * 16 + q * 4;
#pragma unroll
    for (int ni = 0; ni < 4; ++ni) {
      int col = cb + ni * 16 + r;
#pragma unroll
      for (int v = 0; v < 4; ++v) {
        float val = acc[mi][ni][v] + bvv[ni];
        size_t off = (size_t)(rowb + v) * 1024 + col;
        if (out_mode == 0)      ((bf16*)Cout)[off] = (bf16)val;
        else if (out_mode == 1) ((f16*)Cout)[off] = (f16)val;
        else                    ((float*)Cout)[off] = val;
      }
    }
  }
}

// u and v projections fused via grid.z (0: u bf16, 1: v f16). One batch.
__global__ __launch_bounds__(256)
void gemm_uv_k(const bf16* __restrict__ A, const bf16* __restrict__ WuT,
               const bf16* __restrict__ WvT, const float* __restrict__ bu,
               const float* __restrict__ bv, bf16* __restrict__ u_out,
               f16* __restrict__ v_out) {
  const int isv = blockIdx.z;
  gemm_body(A, isv ? WvT : WuT, isv ? bv : bu,
            isv ? (void*)v_out : (void*)u_out, isv,
            blockIdx.x * 128, blockIdx.y * 128);
}

// final projection: C f32
__global__ __launch_bounds__(256)
void gemm_o_k(const bf16* __restrict__ A, const bf16* __restrict__ Bt,
              const float* __restrict__ bias, float* __restrict__ C) {
  gemm_body(A, Bt, bias, (void*)C, 2, blockIdx.x * 128, blockIdx.y * 128);
}

// ---------------------------------------------------------------------------
// Truncated causal depthwise conv (T=512 lags) + gate, in-place p = u * conv.
// One batch (L=4096 rows). Block: 32 d x 128 t. Thread: 1 d, 16 t (sliding
// register window). vg: [L][1024] f16, hp: [dblk][512][32] f16, up: [L][1024].
// ---------------------------------------------------------------------------
__global__ __launch_bounds__(256)
void conv_k(const f16* __restrict__ vg, const f16* __restrict__ hp,
            bf16* __restrict__ up) {
  constexpr int T = 512, KC = 128, D = 1024;
  __shared__ __align__(16) f16 hs[T * 32];     // [k][dd]  32KB
  __shared__ __align__(16) f16 vs[256 * 32];   // [tau][dd] 16KB
  const int tid = threadIdx.x;
  const int dd = tid & 31, tg = tid >> 5;
  const int d0 = blockIdx.x * 32;
  const int t0 = blockIdx.y * 128;
  const int base = tg * 16;

  {  // stage full filter block (contiguous, vectorized)
    const uintx4* src = (const uintx4*)(hp + (size_t)blockIdx.x * T * 32);
    uintx4* dst = (uintx4*)hs;
#pragma unroll
    for (int i = 0; i < 8; ++i) dst[tid + i * 256] = src[tid + i * 256];
  }

  float acc[16];
#pragma unroll
  for (int i = 0; i < 16; ++i) acc[i] = 0.f;

  const unsigned* vg32 = (const unsigned*)vg;
  unsigned* vs32 = (unsigned*)vs;

  for (int c = 0; c < 4; ++c) {
    const int k0 = c * KC;
    __syncthreads();   // also covers hs staging on c==0
    // stage v window: tau in [t0-k0-128, t0-k0+127], zeros for tau<0
#pragma unroll
    for (int it = 0; it < 16; ++it) {
      int w = it * 256 + tid;            // 0..4095 (uint words)
      int to = w >> 4, dp = w & 15;
      int tau = t0 - k0 - 128 + to;
      unsigned val = 0;
      if (tau >= 0) val = vg32[(size_t)tau * (D / 2) + (d0 >> 1) + dp];
      vs32[w] = val;
    }
    __syncthreads();
    float p[16];
#pragma unroll
    for (int i = 0; i < 16; ++i)
      p[i] = (float)vs[(base + i + 128) * 32 + dd];   // lag kk=0
    for (int kb = 0; kb < KC / 16; ++kb) {
#pragma unroll
      for (int k2 = 0; k2 < 16; ++k2) {
        const int kk = kb * 16 + k2;
        float hk = (float)hs[(k0 + kk) * 32 + dd];
#pragma unroll
        for (int i = 0; i < 16; ++i)
          acc[i] += hk * p[(i - k2) & 15];            // phys(i,k)=(i-k)&15
        p[(15 - k2) & 15] = (float)vs[(base + 127 - kk) * 32 + dd];
      }
    }
  }

  // gate: p = u * v_conv, in-place over u (element-local, safe)
  const size_t rb = (size_t)(t0 + base) * D + d0 + dd;
#pragma unroll
  for (int i = 0; i < 16; ++i) {
    float uv = (float)up[rb + (size_t)i * D];
    up[rb + (size_t)i * D] = (bf16)(uv * acc[i]);
  }
}

// ---------------------------------------------------------------------------
// All inputs/outputs are FLOAT32 (per the reference). Internals bf16/f16.
// Workspace use: ws[0..15 MB) only.
//   WuT ws+0 (2MB) | WvT ws+2MB | WoT ws+4MB | hp ws+6MB (1MB) | u_b ws+8MB (8MB)
// Per-batch staging inside the dead d_out quarter (16 MB f32 each):
//   xb_b = quarter+0 (8MB bf16), v_b = quarter+8MB (8MB f16); final gemm_o
//   overwrites the quarter with f32 output after both are dead.
// ---------------------------------------------------------------------------
extern "C" void kernel_launch(void* const* d_in, const int* in_sizes, int n_in,
                              void* d_out, int out_size, void* d_ws,
                              size_t ws_size, hipStream_t stream) {
  const float* x  = (const float*)d_in[0];
  const float* Wu = (const float*)d_in[1];
  const float* bu = (const float*)d_in[2];
  const float* Wv = (const float*)d_in[3];
  const float* bv = (const float*)d_in[4];
  const float* hf = (const float*)d_in[5];
  const float* Wo = (const float*)d_in[6];
  const float* bo = (const float*)d_in[7];
  char* ws = (char*)d_ws;
  bf16* WuT = (bf16*)(ws);
  bf16* WvT = (bf16*)(ws + 2097152);
  bf16* WoT = (bf16*)(ws + 4194304);
  f16*  hp  = (f16*)(ws + 6291456);
  bf16* u_b = (bf16*)(ws + 8388608);

  dim3 tb(256);
  cvtx_k<<<dim3(8192), tb, 0, stream>>>(x, (char*)d_out);
  transpose_k<<<dim3(16, 16, 3), tb, 0, stream>>>(Wu, Wv, Wo, WuT, WvT, WoT);
  hprep_k<<<dim3(2048), tb, 0, stream>>>(hf, hp);
  for (int b = 0; b < 4; ++b) {
    char* quarter = (char*)d_out + (size_t)b * 16777216;
    bf16* xb = (bf16*)quarter;
    f16*  vb = (f16*)(quarter + 8388608);
    float* outb = (float*)d_out + (size_t)b * 4194304;
    gemm_uv_k<<<dim3(32, 8, 2), tb, 0, stream>>>(xb, WuT, WvT, bu, bv,
                                                 u_b, vb);
    conv_k<<<dim3(32, 32), tb, 0, stream>>>(vb, hp, u_b);
    gemm_o_k<<<dim3(32, 8), tb, 0, stream>>>(u_b, WoT, bo, outb);
  }
}

// Round 5
// 516.335 us; speedup vs baseline: 1.2125x; 1.2125x over previous
//
#include <hip/hip_runtime.h>
#include <hip/hip_bf16.h>
#include <hip/hip_fp16.h>
#include <string.h>

typedef __hip_bfloat16 bf16;
typedef _Float16 f16;
typedef __attribute__((ext_vector_type(8))) short short8;
typedef __attribute__((ext_vector_type(4))) float floatx4;
typedef __attribute__((ext_vector_type(4))) unsigned int uintx4;

// async global->LDS, 16B per lane; LDS dest is wave-uniform base + lane*16
#define GLD16(gp, lp) __builtin_amdgcn_global_load_lds( \
    (__attribute__((address_space(1))) void*)(gp),      \
    (__attribute__((address_space(3))) void*)(lp), 16, 0, 0)

__device__ __forceinline__ unsigned short bf16_bits(float f) {
  bf16 h = (bf16)f;
  unsigned short s;
  memcpy(&s, &h, 2);
  return s;
}

// ---------------------------------------------------------------------------
// x (f32, [4][4096][1024]) -> bf16. Batch b lands at outbase + b*bstride.
// (bstride = 8 MB -> contiguous full tensor; 16 MB -> per-d_out-quarter.)
// ---------------------------------------------------------------------------
__global__ __launch_bounds__(256)
void cvtx_k(const float* __restrict__ x, char* __restrict__ outbase,
            size_t bstride) {
  size_t e = ((size_t)blockIdx.x * 256 + threadIdx.x) * 8;
  int b = (int)(e >> 22);                       // 4M elements per batch
  size_t i = e & 4194303;
  const floatx4* s = (const floatx4*)(x + e);
  floatx4 a0 = s[0], a1 = s[1];
  union { uintx4 u4; unsigned short us[8]; } w;
  w.us[0] = bf16_bits(a0.x); w.us[1] = bf16_bits(a0.y);
  w.us[2] = bf16_bits(a0.z); w.us[3] = bf16_bits(a0.w);
  w.us[4] = bf16_bits(a1.x); w.us[5] = bf16_bits(a1.y);
  w.us[6] = bf16_bits(a1.z); w.us[7] = bf16_bits(a1.w);
  *(uintx4*)((bf16*)(outbase + (size_t)b * bstride) + i) = w.u4;
}

// ---------------------------------------------------------------------------
// Transpose+convert 1024x1024 f32 weights: T[n][k] = bf16(W[k][n]), 3 via z.
// ---------------------------------------------------------------------------
__global__ __launch_bounds__(256)
void transpose_k(const float* __restrict__ W0, const float* __restrict__ W1,
                 const float* __restrict__ W2, bf16* __restrict__ T0,
                 bf16* __restrict__ T1, bf16* __restrict__ T2) {
  __shared__ bf16 t[64][66];                 // +2 pad: conflict-free col reads
  const float* S = blockIdx.z == 0 ? W0 : (blockIdx.z == 1 ? W1 : W2);
  bf16* Dst      = blockIdx.z == 0 ? T0 : (blockIdx.z == 1 ? T1 : T2);
  const int tx = threadIdx.x & 63, ty = threadIdx.x >> 6;
  const int kb = blockIdx.y * 64, nb = blockIdx.x * 64;
#pragma unroll
  for (int rr = 0; rr < 16; ++rr) {
    int r = ty * 16 + rr;
    t[r][tx] = (bf16)S[(size_t)(kb + r) * 1024 + nb + tx];
  }
  __syncthreads();
#pragma unroll
  for (int rr = 0; rr < 16; ++rr) {
    int r = ty * 16 + rr;
    Dst[(size_t)(nb + r) * 1024 + kb + tx] = t[tx][r];
  }
}

// ---------------------------------------------------------------------------
// h_prep[dblk][k][dd] = f16( h_filter[k][dblk*32+dd] * exp(-0.01k) ), k<512
// ---------------------------------------------------------------------------
__global__ __launch_bounds__(256)
void hprep_k(const float* __restrict__ hf, f16* __restrict__ hp) {
  int idx = blockIdx.x * 256 + threadIdx.x;   // < 32*512*32
  int dblk = idx >> 14;
  int rem = idx & 16383;
  int k = rem >> 5, dd = rem & 31;
  int d = dblk * 32 + dd;
  float val = hf[(size_t)k * 1024 + d] * __expf(-0.01f * (float)k);
  hp[idx] = (f16)val;
}

// ---------------------------------------------------------------------------
// GEMM body: C[m0..+128][n0..+128] = A[M][1024](bf16) @ Bt[1024][1024]^T + b
// Bt is [n][k] bf16, bias f32. 128x128 tile, BK=32, 4 waves, 4x4 16x16x32.
// out_mode: 0 -> bf16 store, 1 -> f16 store, 2 -> f32 store.
// ---------------------------------------------------------------------------
__device__ __forceinline__
void gemm_body(const bf16* __restrict__ A, const bf16* __restrict__ Bt,
               const float* __restrict__ bias, void* __restrict__ Cout,
               int out_mode, int m0, int n0) {
  constexpr int K = 1024;
  __shared__ __align__(16) bf16 As[128 * 32];   // [m][k], row 64B
  __shared__ __align__(16) bf16 Bs[128 * 32];   // [n][k], row 64B
  const int tid = threadIdx.x;
  const int lane = tid & 63;
  const int wave = tid >> 6;
  const int wm = wave >> 1, wn = wave & 1;
  const int r = lane & 15, q = lane >> 4;

  floatx4 acc[4][4] = {};

  // staging: slot s = issue*256 + tid; row = s>>2, kcol = (s&3)*8
  const int s0 = tid, s1 = 256 + tid;
  const bf16* gA0 = A + (size_t)(m0 + (s0 >> 2)) * K + (s0 & 3) * 8;
  const bf16* gA1 = A + (size_t)(m0 + (s1 >> 2)) * K + (s1 & 3) * 8;
  const bf16* gB0 = Bt + (size_t)(n0 + (s0 >> 2)) * K + (s0 & 3) * 8;
  const bf16* gB1 = Bt + (size_t)(n0 + (s1 >> 2)) * K + (s1 & 3) * 8;
  char* AsB = (char*)As + wave * 1024;   // wave-uniform LDS bases
  char* BsB = (char*)Bs + wave * 1024;

  for (int k0 = 0; k0 < K; k0 += 32) {
    GLD16(gA0 + k0, AsB);
    GLD16(gA1 + k0, AsB + 4096);
    GLD16(gB0 + k0, BsB);
    GLD16(gB1 + k0, BsB + 4096);
    __syncthreads();
    short8 af[4], bfr[4];
#pragma unroll
    for (int i = 0; i < 4; ++i)
      af[i] = *(const short8*)&As[(wm * 64 + i * 16 + r) * 32 + q * 8];
#pragma unroll
    for (int i = 0; i < 4; ++i)
      bfr[i] = *(const short8*)&Bs[(wn * 64 + i * 16 + r) * 32 + q * 8];
#pragma unroll
    for (int mi = 0; mi < 4; ++mi)
#pragma unroll
      for (int ni = 0; ni < 4; ++ni)
        acc[mi][ni] = __builtin_amdgcn_mfma_f32_16x16x32_bf16(
            af[mi], bfr[ni], acc[mi][ni], 0, 0, 0);
    __syncthreads();
  }

  // epilogue: C/D layout col(n)=lane&15, row(m)=(lane>>4)*4+reg
  const int cb = n0 + wn * 64;
  float bvv[4];
#pragma unroll
  for (int ni = 0; ni < 4; ++ni) bvv[ni] = bias[cb + ni * 16 + r];
#pragma unroll
  for (int mi = 0; mi < 4; ++mi) {
    int rowb = m0 + wm * 64 + mi * 16 + q * 4;
#pragma unroll
    for (int ni = 0; ni < 4; ++ni) {
      int col = cb + ni * 16 + r;
#pragma unroll
      for (int v = 0; v < 4; ++v) {
        float val = acc[mi][ni][v] + bvv[ni];
        size_t off = (size_t)(rowb + v) * 1024 + col;
        if (out_mode == 0)      ((bf16*)Cout)[off] = (bf16)val;
        else if (out_mode == 1) ((f16*)Cout)[off] = (f16)val;
        else                    ((float*)Cout)[off] = val;
      }
    }
  }
}

// u and v projections fused via grid.z (0: u bf16, 1: v f16).
__global__ __launch_bounds__(256)
void gemm_uv_k(const bf16* __restrict__ A, const bf16* __restrict__ WuT,
               const bf16* __restrict__ WvT, const float* __restrict__ bu,
               const float* __restrict__ bv, bf16* __restrict__ u_out,
               f16* __restrict__ v_out) {
  const int isv = blockIdx.z;
  gemm_body(A, isv ? WvT : WuT, isv ? bv : bu,
            isv ? (void*)v_out : (void*)u_out, isv,
            blockIdx.x * 128, blockIdx.y * 128);
}

// final projection: C f32
__global__ __launch_bounds__(256)
void gemm_o_k(const bf16* __restrict__ A, const bf16* __restrict__ Bt,
              const float* __restrict__ bias, float* __restrict__ C) {
  gemm_body(A, Bt, bias, (void*)C, 2, blockIdx.x * 128, blockIdx.y * 128);
}

// ---------------------------------------------------------------------------
// Truncated causal depthwise conv (T=512 lags) + gate, in-place p = u * conv.
// Block: 32 d x 128 t; thread: 1 d, 16 t (sliding register window).
// grid.z = batch (4096-row stride). hs is staged PER 128-LAG CHUNK (8 KB),
// so LDS = 24 KB -> 6 blocks/CU (75% occupancy; was 48 KB -> 3 blocks, 23%).
// ---------------------------------------------------------------------------
__global__ __launch_bounds__(256)
void conv_k(const f16* __restrict__ vg0, const f16* __restrict__ hp,
            bf16* __restrict__ up0) {
  constexpr int KC = 128, D = 1024;
  __shared__ __align__(16) f16 hs[KC * 32];    // [kk][dd]  8KB (per chunk)
  __shared__ __align__(16) f16 vs[256 * 32];   // [tau][dd] 16KB
  const int tid = threadIdx.x;
  const int dd = tid & 31, tg = tid >> 5;
  const int d0 = blockIdx.x * 32;
  const int t0 = blockIdx.y * 128;
  const int base = tg * 16;
  const f16* vg = vg0 + (size_t)blockIdx.z * 4096 * D;
  bf16* up = up0 + (size_t)blockIdx.z * 4096 * D;

  float acc[16];
#pragma unroll
  for (int i = 0; i < 16; ++i) acc[i] = 0.f;

  const unsigned* vg32 = (const unsigned*)vg;
  unsigned* vs32 = (unsigned*)vs;
  const uintx4* hsrc = (const uintx4*)(hp + (size_t)blockIdx.x * 512 * 32);
  uintx4* hdst = (uintx4*)hs;

  for (int c = 0; c < 4; ++c) {
    const int k0 = c * KC;
    __syncthreads();   // prev chunk's hs/vs reads complete before restage
    // stage h chunk: 128 lags x 32 dd = 8KB = 512 x 16B
    hdst[tid] = hsrc[k0 * 4 + tid];
    hdst[tid + 256] = hsrc[k0 * 4 + tid + 256];
    // stage v window: tau in [t0-k0-128, t0-k0+127], zeros for tau<0
#pragma unroll
    for (int it = 0; it < 16; ++it) {
      int w = it * 256 + tid;            // 0..4095 (uint words)
      int to = w >> 4, dp = w & 15;
      int tau = t0 - k0 - 128 + to;
      unsigned val = 0;
      if (tau >= 0) val = vg32[(size_t)tau * (D / 2) + (d0 >> 1) + dp];
      vs32[w] = val;
    }
    __syncthreads();
    float p[16];
#pragma unroll
    for (int i = 0; i < 16; ++i)
      p[i] = (float)vs[(base + i + 128) * 32 + dd];   // lag kk=0
    for (int kb = 0; kb < KC / 16; ++kb) {
#pragma unroll
      for (int k2 = 0; k2 < 16; ++k2) {
        const int kk = kb * 16 + k2;
        float hk = (float)hs[kk * 32 + dd];
#pragma unroll
        for (int i = 0; i < 16; ++i)
          acc[i] += hk * p[(i - k2) & 15];            // phys(i,k)=(i-k)&15
        p[(15 - k2) & 15] = (float)vs[(base + 127 - kk) * 32 + dd];
      }
    }
  }

  // gate: p = u * v_conv, in-place over u (element-local, safe)
  const size_t rb = (size_t)(t0 + base) * D + d0 + dd;
#pragma unroll
  for (int i = 0; i < 16; ++i) {
    float uv = (float)up[rb + (size_t)i * D];
    up[rb + (size_t)i * D] = (bf16)(uv * acc[i]);
  }
}

// ---------------------------------------------------------------------------
// All inputs/outputs are FLOAT32. Internals bf16/f16.
// BIG path (ws_size >= 41 MB): full-M (16384) merged dispatches.
//   ws:   WuT 0..2MB | WvT 2..4 | WoT 4..6 | hp 6..7 | u 8..40MB (bf16)
//   d_out: xb (bf16) 0..32MB | v (f16) 32..64MB; gemm_o overwrites with f32.
// COMPACT path (small ws): per-batch loop (round-4 proven layout).
// ---------------------------------------------------------------------------
extern "C" void kernel_launch(void* const* d_in, const int* in_sizes, int n_in,
                              void* d_out, int out_size, void* d_ws,
                              size_t ws_size, hipStream_t stream) {
  const float* x  = (const float*)d_in[0];
  const float* Wu = (const float*)d_in[1];
  const float* bu = (const float*)d_in[2];
  const float* Wv = (const float*)d_in[3];
  const float* bv = (const float*)d_in[4];
  const float* hf = (const float*)d_in[5];
  const float* Wo = (const float*)d_in[6];
  const float* bo = (const float*)d_in[7];
  char* ws = (char*)d_ws;
  bf16* WuT = (bf16*)(ws);
  bf16* WvT = (bf16*)(ws + 2097152);
  bf16* WoT = (bf16*)(ws + 4194304);
  f16*  hp  = (f16*)(ws + 6291456);

  dim3 tb(256);
  transpose_k<<<dim3(16, 16, 3), tb, 0, stream>>>(Wu, Wv, Wo, WuT, WvT, WoT);
  hprep_k<<<dim3(2048), tb, 0, stream>>>(hf, hp);

  if (ws_size >= 42991616ull) {           // BIG: 41 MB needed
    bf16* xb = (bf16*)d_out;
    f16*  vf = (f16*)((char*)d_out + 33554432);
    bf16* u  = (bf16*)(ws + 8388608);
    cvtx_k<<<dim3(8192), tb, 0, stream>>>(x, (char*)d_out, 8388608);
    gemm_uv_k<<<dim3(128, 8, 2), tb, 0, stream>>>(xb, WuT, WvT, bu, bv, u, vf);
    conv_k<<<dim3(32, 32, 4), tb, 0, stream>>>(vf, hp, u);
    gemm_o_k<<<dim3(128, 8), tb, 0, stream>>>(u, WoT, bo, (float*)d_out);
  } else {                                // COMPACT: per-batch (round-4)
    bf16* u_b = (bf16*)(ws + 8388608);
    cvtx_k<<<dim3(8192), tb, 0, stream>>>(x, (char*)d_out, 16777216);
    for (int b = 0; b < 4; ++b) {
      char* quarter = (char*)d_out + (size_t)b * 16777216;
      bf16* xb = (bf16*)quarter;
      f16*  vb = (f16*)(quarter + 8388608);
      float* outb = (float*)d_out + (size_t)b * 4194304;
      gemm_uv_k<<<dim3(32, 8, 2), tb, 0, stream>>>(xb, WuT, WvT, bu, bv,
                                                   u_b, vb);
      conv_k<<<dim3(32, 32, 1), tb, 0, stream>>>(vb, hp, u_b);
      gemm_o_k<<<dim3(32, 8), tb, 0, stream>>>(u_b, WoT, bo, outb);
    }
  }
}

// Round 6
// 436.427 us; speedup vs baseline: 1.4345x; 1.1831x over previous
//
#include <hip/hip_runtime.h>
#include <hip/hip_bf16.h>
#include <hip/hip_fp16.h>
#include <string.h>

typedef __hip_bfloat16 bf16;
typedef _Float16 f16;
typedef __attribute__((ext_vector_type(8))) short short8;
typedef __attribute__((ext_vector_type(4))) float floatx4;
typedef __attribute__((ext_vector_type(4))) unsigned int uintx4;

// async global->LDS, 16B per lane; LDS dest is wave-uniform base + lane*16
#define GLD16(gp, lp) __builtin_amdgcn_global_load_lds( \
    (__attribute__((address_space(1))) void*)(gp),      \
    (__attribute__((address_space(3))) void*)(lp), 16, 0, 0)

__device__ __forceinline__ unsigned short bf16_bits(float f) {
  bf16 h = (bf16)f;
  unsigned short s;
  memcpy(&s, &h, 2);
  return s;
}
__device__ __forceinline__ __half2 u2h2(unsigned u) {
  __half2 h;
  memcpy(&h, &u, 4);
  return h;
}

// ---------------------------------------------------------------------------
// x (f32, [4][4096][1024]) -> bf16. Batch b lands at outbase + b*bstride.
// ---------------------------------------------------------------------------
__global__ __launch_bounds__(256)
void cvtx_k(const float* __restrict__ x, char* __restrict__ outbase,
            size_t bstride) {
  size_t e = ((size_t)blockIdx.x * 256 + threadIdx.x) * 8;
  int b = (int)(e >> 22);                       // 4M elements per batch
  size_t i = e & 4194303;
  const floatx4* s = (const floatx4*)(x + e);
  floatx4 a0 = s[0], a1 = s[1];
  union { uintx4 u4; unsigned short us[8]; } w;
  w.us[0] = bf16_bits(a0.x); w.us[1] = bf16_bits(a0.y);
  w.us[2] = bf16_bits(a0.z); w.us[3] = bf16_bits(a0.w);
  w.us[4] = bf16_bits(a1.x); w.us[5] = bf16_bits(a1.y);
  w.us[6] = bf16_bits(a1.z); w.us[7] = bf16_bits(a1.w);
  *(uintx4*)((bf16*)(outbase + (size_t)b * bstride) + i) = w.u4;
}

// ---------------------------------------------------------------------------
// Transpose+convert 1024x1024 f32 weights: T[n][k] = bf16(W[k][n]), 3 via z.
// ---------------------------------------------------------------------------
__global__ __launch_bounds__(256)
void transpose_k(const float* __restrict__ W0, const float* __restrict__ W1,
                 const float* __restrict__ W2, bf16* __restrict__ T0,
                 bf16* __restrict__ T1, bf16* __restrict__ T2) {
  __shared__ bf16 t[64][66];                 // +2 pad: conflict-free col reads
  const float* S = blockIdx.z == 0 ? W0 : (blockIdx.z == 1 ? W1 : W2);
  bf16* Dst      = blockIdx.z == 0 ? T0 : (blockIdx.z == 1 ? T1 : T2);
  const int tx = threadIdx.x & 63, ty = threadIdx.x >> 6;
  const int kb = blockIdx.y * 64, nb = blockIdx.x * 64;
#pragma unroll
  for (int rr = 0; rr < 16; ++rr) {
    int r = ty * 16 + rr;
    t[r][tx] = (bf16)S[(size_t)(kb + r) * 1024 + nb + tx];
  }
  __syncthreads();
#pragma unroll
  for (int rr = 0; rr < 16; ++rr) {
    int r = ty * 16 + rr;
    Dst[(size_t)(nb + r) * 1024 + kb + tx] = t[tx][r];
  }
}

// ---------------------------------------------------------------------------
// h_prep[dblk64][k][dd] = f16( h_filter[k][dblk*64+dd] * exp(-0.01k) ), k<512
// ---------------------------------------------------------------------------
__global__ __launch_bounds__(256)
void hprep_k(const float* __restrict__ hf, f16* __restrict__ hp) {
  int idx = blockIdx.x * 256 + threadIdx.x;   // < 16*512*64
  int dblk = idx >> 15;
  int rem = idx & 32767;
  int k = rem >> 6, dd = rem & 63;
  int d = dblk * 64 + dd;
  float val = hf[(size_t)k * 1024 + d] * __expf(-0.01f * (float)k);
  hp[idx] = (f16)val;
}

// ---------------------------------------------------------------------------
// GEMM body: C[m0..+128][n0..+128] = A[M][1024](bf16) @ Bt[1024][1024]^T + b
// Bt is [n][k] bf16, bias f32. 128x128 tile, BK=32, 4 waves, 4x4 16x16x32.
// out_mode: 0 -> bf16 store, 1 -> f16 store, 2 -> f32 store.
// ---------------------------------------------------------------------------
__device__ __forceinline__
void gemm_body(const bf16* __restrict__ A, const bf16* __restrict__ Bt,
               const float* __restrict__ bias, void* __restrict__ Cout,
               int out_mode, int m0, int n0) {
  constexpr int K = 1024;
  __shared__ __align__(16) bf16 As[128 * 32];   // [m][k], row 64B
  __shared__ __align__(16) bf16 Bs[128 * 32];   // [n][k], row 64B
  const int tid = threadIdx.x;
  const int lane = tid & 63;
  const int wave = tid >> 6;
  const int wm = wave >> 1, wn = wave & 1;
  const int r = lane & 15, q = lane >> 4;

  floatx4 acc[4][4] = {};

  // staging: slot s = issue*256 + tid; row = s>>2, kcol = (s&3)*8
  const int s0 = tid, s1 = 256 + tid;
  const bf16* gA0 = A + (size_t)(m0 + (s0 >> 2)) * K + (s0 & 3) * 8;
  const bf16* gA1 = A + (size_t)(m0 + (s1 >> 2)) * K + (s1 & 3) * 8;
  const bf16* gB0 = Bt + (size_t)(n0 + (s0 >> 2)) * K + (s0 & 3) * 8;
  const bf16* gB1 = Bt + (size_t)(n0 + (s1 >> 2)) * K + (s1 & 3) * 8;
  char* AsB = (char*)As + wave * 1024;   // wave-uniform LDS bases
  char* BsB = (char*)Bs + wave * 1024;

  for (int k0 = 0; k0 < K; k0 += 32) {
    GLD16(gA0 + k0, AsB);
    GLD16(gA1 + k0, AsB + 4096);
    GLD16(gB0 + k0, BsB);
    GLD16(gB1 + k0, BsB + 4096);
    __syncthreads();
    short8 af[4], bfr[4];
#pragma unroll
    for (int i = 0; i < 4; ++i)
      af[i] = *(const short8*)&As[(wm * 64 + i * 16 + r) * 32 + q * 8];
#pragma unroll
    for (int i = 0; i < 4; ++i)
      bfr[i] = *(const short8*)&Bs[(wn * 64 + i * 16 + r) * 32 + q * 8];
#pragma unroll
    for (int mi = 0; mi < 4; ++mi)
#pragma unroll
      for (int ni = 0; ni < 4; ++ni)
        acc[mi][ni] = __builtin_amdgcn_mfma_f32_16x16x32_bf16(
            af[mi], bfr[ni], acc[mi][ni], 0, 0, 0);
    __syncthreads();
  }

  // epilogue: C/D layout col(n)=lane&15, row(m)=(lane>>4)*4+reg
  const int cb = n0 + wn * 64;
  float bvv[4];
#pragma unroll
  for (int ni = 0; ni < 4; ++ni) bvv[ni] = bias[cb + ni * 16 + r];
#pragma unroll
  for (int mi = 0; mi < 4; ++mi) {
    int rowb = m0 + wm * 64 + mi * 16 + q * 4;
#pragma unroll
    for (int ni = 0; ni < 4; ++ni) {
      int col = cb + ni * 16 + r;
#pragma unroll
      for (int v = 0; v < 4; ++v) {
        float val = acc[mi][ni][v] + bvv[ni];
        size_t off = (size_t)(rowb + v) * 1024 + col;
        if (out_mode == 0)      ((bf16*)Cout)[off] = (bf16)val;
        else if (out_mode == 1) ((f16*)Cout)[off] = (f16)val;
        else                    ((float*)Cout)[off] = val;
      }
    }
  }
}

// u and v projections fused via grid.z (0: u bf16, 1: v f16).
__global__ __launch_bounds__(256)
void gemm_uv_k(const bf16* __restrict__ A, const bf16* __restrict__ WuT,
               const bf16* __restrict__ WvT, const float* __restrict__ bu,
               const float* __restrict__ bv, bf16* __restrict__ u_out,
               f16* __restrict__ v_out) {
  const int isv = blockIdx.z;
  gemm_body(A, isv ? WvT : WuT, isv ? bv : bu,
            isv ? (void*)v_out : (void*)u_out, isv,
            blockIdx.x * 128, blockIdx.y * 128);
}

// final projection: C f32
__global__ __launch_bounds__(256)
void gemm_o_k(const bf16* __restrict__ A, const bf16* __restrict__ Bt,
              const float* __restrict__ bias, float* __restrict__ C) {
  gemm_body(A, Bt, bias, (void*)C, 2, blockIdx.x * 128, blockIdx.y * 128);
}

// ---------------------------------------------------------------------------
// Truncated causal depthwise conv (T=512) + gate, packed f16x2 along d.
// Block: 64 d (32 __half2 pairs) x 128 t; thread: 1 d-pair, 16 t.
// Chunk = 64 lags; acc in f16x2 per chunk, flushed to f32. All inner-loop
// math is v_pk_fma_f16 (2 MACs/inst); zero cvts in the hot loop.
// LDS: vs 192x32 u32 (24KB) + hs 64x32 u32 (8KB) = 32KB -> 5 blocks/CU.
// ---------------------------------------------------------------------------
__global__ __launch_bounds__(256)
void conv_k(const f16* __restrict__ vg0, const f16* __restrict__ hp,
            bf16* __restrict__ up0) {
  constexpr int CC = 64, TT = 128, D = 1024;
  __shared__ __align__(16) unsigned vs2[(TT + CC) * 32];  // [row][pair] 24KB
  __shared__ __align__(16) unsigned hs2[CC * 32];         // [kk][pair]   8KB
  const int tid = threadIdx.x;
  const int pp = tid & 31, tg = tid >> 5;
  const int bx = blockIdx.x;                 // d0 = bx*64
  const int t0 = blockIdx.y * TT;
  const int base = tg * 16;
  const unsigned* vg32 = (const unsigned*)(vg0 + (size_t)blockIdx.z * 4096 * D);
  unsigned* up32 = (unsigned*)(up0 + (size_t)blockIdx.z * 4096 * D);
  const uintx4* vg4 = (const uintx4*)vg32;             // 128 u4 per t-row
  const uintx4* hp4 = (const uintx4*)hp + (size_t)bx * 512 * 8;  // 8 u4/row

  float ax[16], ay[16];
#pragma unroll
  for (int i = 0; i < 16; ++i) { ax[i] = 0.f; ay[i] = 0.f; }

  for (int c = 0; c < 8; ++c) {
    const int k0 = c * CC;
    __syncthreads();   // prev chunk's reads complete before restage
    {  // stage h chunk: 64 rows x 8 u4 = 512 u4
      uintx4* hd = (uintx4*)hs2;
      hd[tid] = hp4[k0 * 8 + tid];
      hd[tid + 256] = hp4[k0 * 8 + tid + 256];
    }
    {  // stage v window rows [t0-k0-64, t0+127]: 192 x 8 u4 = 1536 u4
      uintx4* vd = (uintx4*)vs2;
#pragma unroll
      for (int it = 0; it < 6; ++it) {
        int q = it * 256 + tid;
        int row = q >> 3, dp4 = q & 7;
        int tau = t0 - k0 - CC + row;
        uintx4 val = {0, 0, 0, 0};
        if (tau >= 0) val = vg4[(size_t)tau * 128 + bx * 8 + dp4];
        vd[q] = val;
      }
    }
    __syncthreads();

    __half2 p[16];
#pragma unroll
    for (int i = 0; i < 16; ++i)
      p[i] = u2h2(vs2[(base + i + CC) * 32 + pp]);     // v[t_i - k0]
    __half2 acc2[16];
    const __half2 z2 = __float2half2_rn(0.f);
#pragma unroll
    for (int i = 0; i < 16; ++i) acc2[i] = z2;

    for (int kb = 0; kb < 4; ++kb) {
#pragma unroll
      for (int k2 = 0; k2 < 16; ++k2) {
        const int kk = kb * 16 + k2;
        __half2 hk = u2h2(hs2[kk * 32 + pp]);
#pragma unroll
        for (int i = 0; i < 16; ++i)
          acc2[i] = __hfma2(hk, p[(i - k2) & 15], acc2[i]);
        p[(15 - k2) & 15] = u2h2(vs2[(base + CC - 1 - kk) * 32 + pp]);
      }
    }
#pragma unroll
    for (int i = 0; i < 16; ++i) {
      ax[i] += __low2float(acc2[i]);
      ay[i] += __high2float(acc2[i]);
    }
  }

  // gate: p = u * v_conv, in-place over u; one u32 = 2 bf16 per row
  const size_t rb = (size_t)(t0 + base) * 512 + bx * 32 + pp;
#pragma unroll
  for (int i = 0; i < 16; ++i) {
    unsigned uw = up32[rb + (size_t)i * 512];
    float ul = __uint_as_float((uw & 0xffffu) << 16);
    float uh = __uint_as_float(uw & 0xffff0000u);
    unsigned lo = bf16_bits(ul * ax[i]);
    unsigned hi = bf16_bits(uh * ay[i]);
    up32[rb + (size_t)i * 512] = lo | (hi << 16);
  }
}

// ---------------------------------------------------------------------------
// All inputs/outputs are FLOAT32. Internals bf16/f16.
// BIG path (ws_size >= 41 MB): full-M merged dispatches.
//   ws:   WuT 0..2MB | WvT 2..4 | WoT 4..6 | hp 6..7 | u 8..40MB (bf16)
//   d_out: xb (bf16) 0..32MB | v (f16) 32..64MB; gemm_o overwrites with f32.
// COMPACT path: per-batch loop (round-4 proven layout).
// ---------------------------------------------------------------------------
extern "C" void kernel_launch(void* const* d_in, const int* in_sizes, int n_in,
                              void* d_out, int out_size, void* d_ws,
                              size_t ws_size, hipStream_t stream) {
  const float* x  = (const float*)d_in[0];
  const float* Wu = (const float*)d_in[1];
  const float* bu = (const float*)d_in[2];
  const float* Wv = (const float*)d_in[3];
  const float* bv = (const float*)d_in[4];
  const float* hf = (const float*)d_in[5];
  const float* Wo = (const float*)d_in[6];
  const float* bo = (const float*)d_in[7];
  char* ws = (char*)d_ws;
  bf16* WuT = (bf16*)(ws);
  bf16* WvT = (bf16*)(ws + 2097152);
  bf16* WoT = (bf16*)(ws + 4194304);
  f16*  hp  = (f16*)(ws + 6291456);

  dim3 tb(256);
  transpose_k<<<dim3(16, 16, 3), tb, 0, stream>>>(Wu, Wv, Wo, WuT, WvT, WoT);
  hprep_k<<<dim3(2048), tb, 0, stream>>>(hf, hp);

  if (ws_size >= 42991616ull) {           // BIG: 41 MB needed
    bf16* xb = (bf16*)d_out;
    f16*  vf = (f16*)((char*)d_out + 33554432);
    bf16* u  = (bf16*)(ws + 8388608);
    cvtx_k<<<dim3(8192), tb, 0, stream>>>(x, (char*)d_out, 8388608);
    gemm_uv_k<<<dim3(128, 8, 2), tb, 0, stream>>>(xb, WuT, WvT, bu, bv, u, vf);
    conv_k<<<dim3(16, 32, 4), tb, 0, stream>>>(vf, hp, u);
    gemm_o_k<<<dim3(128, 8), tb, 0, stream>>>(u, WoT, bo, (float*)d_out);
  } else {                                // COMPACT: per-batch (round-4)
    bf16* u_b = (bf16*)(ws + 8388608);
    cvtx_k<<<dim3(8192), tb, 0, stream>>>(x, (char*)d_out, 16777216);
    for (int b = 0; b < 4; ++b) {
      char* quarter = (char*)d_out + (size_t)b * 16777216;
      bf16* xb = (bf16*)quarter;
      f16*  vb = (f16*)(quarter + 8388608);
      float* outb = (float*)d_out + (size_t)b * 4194304;
      gemm_uv_k<<<dim3(32, 8, 2), tb, 0, stream>>>(xb, WuT, WvT, bu, bv,
                                                   u_b, vb);
      conv_k<<<dim3(16, 32, 1), tb, 0, stream>>>(vb, hp, u_b);
      gemm_o_k<<<dim3(32, 8), tb, 0, stream>>>(u_b, WoT, bo, outb);
    }
  }
}